// Round 1
// 154.294 us; speedup vs baseline: 1.1861x; 1.1861x over previous
//
#include <hip/hip_runtime.h>
#include <hip/hip_bf16.h>
#include <math.h>

#define NS 4096      // samples
#define NC 512       // clusters
#define ND 64        // feature dim
#define NK 10        // classes
#define NPAIR 2080   // upper-triangle pairs (e<=d) of 64x64
#define KP 2176      // 2080 + 64 (linear) + 1 (const) + 31 zero-pad; 68*32
#define BOFF 2080
#define KOFF 2144
#define KSPLIT 4
#define KT_PER (KP / 32 / KSPLIT)   // 17 k-chunks per split block
#define ZB 1024                     // d2-zeroing blocks

typedef __attribute__((ext_vector_type(8))) short short8;
typedef __attribute__((ext_vector_type(4))) float floatx4;

__device__ inline unsigned short f2b(float x) {
    __hip_bfloat16 h = __float2bfloat16(x);           // RNE
    return __builtin_bit_cast(unsigned short, h);
}
__device__ inline float b2f(unsigned short u) {
    __hip_bfloat16 h = __builtin_bit_cast(__hip_bfloat16, u);
    return __bfloat162float(h);
}

// true v_readlane_b32 (lane is a compile-time literal at every use site)
__device__ inline float rlane(float v, int k) {
    return __builtin_bit_cast(float, __builtin_amdgcn_readlane(__builtin_bit_cast(int, v), k));
}

// async global->LDS, 16B per lane (m97 lever); dst = wave-uniform base + lane*16
__device__ inline void gl16(const void* g, void* l) {
    __builtin_amdgcn_global_load_lds(
        (const __attribute__((address_space(1))) unsigned int*)g,
        (__attribute__((address_space(3))) unsigned int*)l, 16, 0, 0);
}

// ---------------- (e,d) table with sentinels: val[p] = z[e]*z[d] ------------
__global__ void table_kernel(int2* __restrict__ edt) {
    const int e = threadIdx.x;                        // 64 threads
    int off = e * 64 - (e * (e - 1)) / 2;             // row e starts here
    for (int d = e; d < 64; ++d) edt[off + d - e] = make_int2(e, d);
    edt[BOFF + e] = make_int2(e, 64);                 // linear terms: z*1
    if (e == 0) edt[KOFF] = make_int2(64, 64);        // const term: 1
    if (e < KP - KOFF - 1) edt[KOFF + 1 + e] = make_int2(65, 65);   // pad: 0
}

// ---------------- prep (Sigma^-1 + beta pack) + d2 zeroing ------------------
// R16 core: 4-WAVE COOPERATIVE Gauss-Jordan (R15 was 1 wave; waves 1-3 idle ->
// 0.5 waves/SIMD, VALUBusy 21%, 59.4us).
//  * wave w owns rows 16w..16w+15 of all 64 columns: 4 float4 regs/lane
//    (vs 16) -> per-wave issue /4;
//  * per step k: owner wave (w == k>>4) computes normalized row k, publishes
//    via double-buffered LDS rowbuf[k&1][64]; ONE __syncthreads per step;
//  * column broadcast c_i = readlane(B_i, k) stays wave-local (each wave holds
//    its rows for ALL 64 columns);
//  * arithmetic bit-identical to R15: same FMA operands in the same order;
//    rowk passes through LDS as an exact f32.
// Epilogue: mirror to AcolS (all 4 waves), wave 0 recomputes y with the SAME
// expression shape (reads its column back from LDS), pack loop split 4 ways.
__global__ __launch_bounds__(256, 4) void prep_kernel(
    const float* __restrict__ S, const float* __restrict__ n,
    const float* __restrict__ mu, const int* __restrict__ clab,
    const int2* __restrict__ edt, unsigned short* __restrict__ Bph,
    unsigned short* __restrict__ Bpl, float* __restrict__ d2,
    float* __restrict__ labf)
{
    __shared__ float AcolS[ND * (ND + 1)];            // Sinv mirror [64][65]
    __shared__ float cbuf[ND];                        // bvec staging
    __shared__ float rowbuf[2][ND];                   // GJ pivot-row broadcast
    __shared__ float kksS[1];

    if (blockIdx.x >= NC) {                           // ---- d2 zero role ----
        const size_t base = (size_t)(blockIdx.x - NC) * 2048 + threadIdx.x * 8;
        *(float4*)&d2[base]     = make_float4(0.f, 0.f, 0.f, 0.f);
        *(float4*)&d2[base + 4] = make_float4(0.f, 0.f, 0.f, 0.f);
        return;
    }

    const int c = blockIdx.x;
    const int tid = threadIdx.x;
    const int j = tid & 63;                           // column owned by lane
    const int w = tid >> 6;                           // wave -> rows 16w..16w+15
    const int rbase = w * 16;

    const float inv_nc = 1.0f / n[c];
    const float* __restrict__ Sc = S + (size_t)c * ND * ND + j;

    float4 B0, B1, B2, B3;
#define LOADR(u) {                                                   \
    const float x0 = Sc[(rbase + 4*(u) + 0) * ND] * inv_nc;          \
    const float x1 = Sc[(rbase + 4*(u) + 1) * ND] * inv_nc;          \
    const float x2 = Sc[(rbase + 4*(u) + 2) * ND] * inv_nc;         \
    const float x3 = Sc[(rbase + 4*(u) + 3) * ND] * inv_nc;          \
    B##u.x = (rbase + 4*(u) + 0 == j) ? x0 + 1e-6f : x0;             \
    B##u.y = (rbase + 4*(u) + 1 == j) ? x1 + 1e-6f : x1;             \
    B##u.z = (rbase + 4*(u) + 2 == j) ? x2 + 1e-6f : x2;             \
    B##u.w = (rbase + 4*(u) + 3 == j) ? x3 + 1e-6f : x3; }
    LOADR(0) LOADR(1) LOADR(2) LOADR(3)
#undef LOADR

    // ---- 64 fully-unrolled GJ steps (k literal everywhere) ----
    // row fixup (row==k) folds: literal local-row test && wave-uniform om.
#define UPD4(u, K) {                                                  \
    const float c0 = rlane(B##u.x, K);                                \
    const float c1 = rlane(B##u.y, K);                                \
    const float c2 = rlane(B##u.z, K);                                \
    const float c3 = rlane(B##u.w, K);                                \
    B##u.x = (om && (4*(u)+0 == ((K)&15))) ? rowk : B##u.x * am - c0 * rowk; \
    B##u.y = (om && (4*(u)+1 == ((K)&15))) ? rowk : B##u.y * am - c1 * rowk; \
    B##u.z = (om && (4*(u)+2 == ((K)&15))) ? rowk : B##u.z * am - c2 * rowk; \
    B##u.w = (om && (4*(u)+3 == ((K)&15))) ? rowk : B##u.w * am - c3 * rowk; \
}
#define STEPC(TL, C, K) {                                             \
    if (w == ((K) >> 4)) {                                            \
        const float rp = B##TL.C;         /* M[k][j]: own register */ \
        const float pv = rlane(rp, K);    /* pivot M[k][k] */         \
        const float ip = 1.0f / pv;                                   \
        rowbuf[(K) & 1][j] = (j == (K)) ? ip : rp * ip;               \
    }                                                                 \
    __syncthreads();                                                  \
    const float rowk = rowbuf[(K) & 1][j];                            \
    const float am = (j == (K)) ? 0.0f : 1.0f;                        \
    const bool om = (w == ((K) >> 4));                                \
    UPD4(0, K) UPD4(1, K) UPD4(2, K) UPD4(3, K)                       \
}
#define STEP4(T, TL) STEPC(TL, x, 4*(T)+0) STEPC(TL, y, 4*(T)+1) \
                     STEPC(TL, z, 4*(T)+2) STEPC(TL, w, 4*(T)+3)
#define FOR16P(M) M(0,0) M(1,1) M(2,2) M(3,3) M(4,0) M(5,1) M(6,2) M(7,3) \
                  M(8,0) M(9,1) M(10,2) M(11,3) M(12,0) M(13,1) M(14,2) M(15,3)
    FOR16P(STEP4)
#undef FOR16P
#undef STEP4
#undef STEPC
#undef UPD4

    // mirror Sinv into LDS for the pack gather (all 4 waves, disjoint rows)
#define MIR(u) *(float4*)&AcolS[j * (ND + 1) + rbase + 4*(u)] = B##u;
    MIR(0) MIR(1) MIR(2) MIR(3)
#undef MIR
    __syncthreads();                                  // AcolS complete

    if (w == 0) {                                     // y = Sinv*mu, kk, labels
        const float* __restrict__ muc = mu + (size_t)c * ND;
        float y = 0.f;
        #pragma unroll
        for (int t = 0; t < 16; ++t) {
            const float4 v = *(const float4*)&AcolS[j * (ND + 1) + 4 * t];
            y += v.x * muc[4*t]     + v.y * muc[4*t + 1]
               + v.z * muc[4*t + 2] + v.w * muc[4*t + 3];
        }
        cbuf[j] = -2.0f * y;                          // bvec values
        float kk = muc[j] * y;
        #pragma unroll
        for (int off = 32; off > 0; off >>= 1) kk += __shfl_down(kk, off);
        if (j == 0) {
            kksS[0] = kk;
            int lab = 0;
            for (int q = 0; q < NK; ++q) if (clab[c * NK + q] != 0) lab = q;
            labf[c] = (float)lab;
        }
    }
    __syncthreads();
    const float kks = kksS[0];

    unsigned short* __restrict__ ph = Bph + (size_t)c * KP;
    unsigned short* __restrict__ pl = Bpl + (size_t)c * KP;
    #pragma unroll
    for (int i = 0; i < 9; ++i) {                     // 34 iters split 4 ways
        const int t = w + 4 * i;
        if (t < KP / 64) {
            const int p = t * 64 + j;
            float val;
            if (p < NPAIR) {
                const int2 ed = edt[p];
                val = (ed.x == ed.y) ? AcolS[ed.x * (ND + 1) + ed.x]
                    : (AcolS[ed.y * (ND + 1) + ed.x] + AcolS[ed.x * (ND + 1) + ed.y]);
            } else if (p < KOFF) val = cbuf[p - BOFF];
            else if (p == KOFF)  val = kks;
            else                 val = 0.f;
            const unsigned short h = f2b(val);
            const unsigned short l = f2b(val - b2f(h));
            ph[p] = h;
            pl[p] = l;
        }
    }
}

// ---------------- d2 = Q·Beta^T, Q built on the fly; 64x256 tile, split-K x4 -
// R16: B-tile XOR swizzle (T2, both-sides-or-neither per rule 21). B rows are
// 64B -> b128 frag reads collapsed to 2/8 bank groups per 16-lane phase
// (SQ_LDS_BANK_CONFLICT 2.84M/dispatch). Segment slot s holds global chunk
// s ^ ((row>>2)&3): staged by pre-swizzling the per-lane GLOBAL source address
// (gl16's LDS dst must stay linear), read back with the same XOR. Staged bits
// and MFMA inputs are unchanged -> d2 bit-identical.
__global__ __launch_bounds__(256, 2) void gemm_kernel(
    const float* __restrict__ data, const int2* __restrict__ edt,
    const unsigned short* __restrict__ Bph, const unsigned short* __restrict__ Bpl,
    float* __restrict__ d2)
{
    __shared__ float zS[64 * 68];                             // z-tile + sentinels
    __shared__ unsigned short AhS[64 * 40], AlS[64 * 40];     // 5KB each
    __shared__ unsigned short BhS[256 * 32], BlS[256 * 32];   // 16KB each

    const int tid  = threadIdx.x;
    const int lane = tid & 63, w = tid >> 6;
    const int quad = lane >> 4, rlo = lane & 15;
    const int m0 = blockIdx.x * 64;      // sample tile
    const int n0 = blockIdx.y * 256;     // cluster tile
    const int koff0 = blockIdx.z * KT_PER * 32;   // this block's K-slice start

    #pragma unroll
    for (int q = 0; q < 4; ++q) {
        const int f = q * 256 + tid;                  // float4 id
        const int r = f >> 4, c4 = f & 15;
        const float4 v = *(const float4*)&data[(size_t)(m0 + r) * ND + c4 * 4];
        *(float4*)&zS[r * 68 + c4 * 4] = v;
    }
    if (tid < 64) { zS[tid * 68 + 64] = 1.0f; zS[tid * 68 + 65] = 0.0f; }

    const int brow = tid >> 2, bseg = tid & 3;
    const int sseg = bseg ^ ((brow >> 2) & 3);        // pre-swizzled source seg
    const unsigned short* bGh[4];
    const unsigned short* bGl[4];
    unsigned short* bLh[4];
    unsigned short* bLl[4];
    #pragma unroll
    for (int rd = 0; rd < 4; ++rd) {
        const size_t off = (size_t)(n0 + rd * 64 + brow) * KP + sseg * 8 + koff0;
        bGh[rd] = Bph + off;
        bGl[rd] = Bpl + off;
        bLh[rd] = BhS + (rd * 256 + tid) * 8;         // lane*16B contiguous
        bLl[rd] = BlS + (rd * 256 + tid) * 8;
    }

    const int jc = (tid & 15) * 2;                    // cols jc, jc+1
    const int rb = (tid >> 4) * 4;                    // rows rb..rb+3
    const int bswz = (quad ^ ((rlo >> 2) & 3)) * 8;   // swizzled read slot

    floatx4 acc[4][4] = {};
    __syncthreads();                                  // z-tile visible

    for (int kt = 0; kt < KT_PER; ++kt) {
        const int ko = kt * 32;
        if (kt) __syncthreads();                      // frags consumed
        #pragma unroll
        for (int rd = 0; rd < 4; ++rd) {
            gl16(bGh[rd] + ko, bLh[rd]);
            gl16(bGl[rd] + ko, bLl[rd]);
        }
        const int2 ed0 = edt[koff0 + ko + jc];
        const int2 ed1 = edt[koff0 + ko + jc + 1];
        #pragma unroll
        for (int rr = 0; rr < 4; ++rr) {
            const int r = rb + rr;
            const float* zr = &zS[r * 68];
            const float v0 = zr[ed0.x] * zr[ed0.y];
            const float v1 = zr[ed1.x] * zr[ed1.y];
            const unsigned short h0 = f2b(v0), h1 = f2b(v1);
            const unsigned short l0 = f2b(v0 - b2f(h0)), l1 = f2b(v1 - b2f(h1));
            *(unsigned*)&AhS[r * 40 + jc] = (unsigned)h0 | ((unsigned)h1 << 16);
            *(unsigned*)&AlS[r * 40 + jc] = (unsigned)l0 | ((unsigned)l1 << 16);
        }
        __syncthreads();                              // staging + A visible

        short8 ah[4], al[4], bh[4], bl[4];
        #pragma unroll
        for (int i = 0; i < 4; ++i) {
            ah[i] = *(const short8*)&AhS[(i * 16 + rlo) * 40 + quad * 8];
            al[i] = *(const short8*)&AlS[(i * 16 + rlo) * 40 + quad * 8];
        }
        #pragma unroll
        for (int j2 = 0; j2 < 4; ++j2) {
            const int r = w * 64 + j2 * 16 + rlo;
            bh[j2] = *(const short8*)&BhS[r * 32 + bswz];
            bl[j2] = *(const short8*)&BlS[r * 32 + bswz];
        }
        #pragma unroll
        for (int i = 0; i < 4; ++i)
            #pragma unroll
            for (int j2 = 0; j2 < 4; ++j2) {
                acc[i][j2] = __builtin_amdgcn_mfma_f32_16x16x32_bf16(al[i], bh[j2], acc[i][j2], 0, 0, 0);
                acc[i][j2] = __builtin_amdgcn_mfma_f32_16x16x32_bf16(ah[i], bl[j2], acc[i][j2], 0, 0, 0);
                acc[i][j2] = __builtin_amdgcn_mfma_f32_16x16x32_bf16(ah[i], bh[j2], acc[i][j2], 0, 0, 0);
            }
    }

    // C layout (verified m89): col = lane&15, row = (lane>>4)*4 + reg
    #pragma unroll
    for (int i = 0; i < 4; ++i)
        #pragma unroll
        for (int j2 = 0; j2 < 4; ++j2) {
            const int m = m0 + i * 16 + quad * 4;
            const int nn = n0 + w * 64 + j2 * 16 + rlo;
            #pragma unroll
            for (int r = 0; r < 4; ++r)
                atomicAdd(&d2[(size_t)(m + r) * NC + nn], acc[i][j2][r]);
        }
}

// ---------------- scores / argmaxes: 4 waves/block, one sample per wave -----
__global__ __launch_bounds__(256) void score_kernel(
    const float* __restrict__ d2, const float* __restrict__ labf,
    float* __restrict__ out)
{
    const int s = blockIdx.x * 4 + (threadIdx.x >> 6);
    const int l = threadIdx.x & 63;

    float numer[NK];
    #pragma unroll
    for (int q = 0; q < NK; ++q) numer[q] = 0.f;
    float denom = 0.f, gmax = -1.f;
    int gidx = 0;

    #pragma unroll
    for (int i = 0; i < NC / 256; ++i) {         // float4 per lane, index-ascending
        const int c0 = i * 256 + l * 4;
        const float4 v = *(const float4*)&d2[(size_t)s * NC + c0];
        #pragma unroll
        for (int r = 0; r < 4; ++r) {
            const int c = c0 + r;
            const float G = __expf(-0.5f * ((const float*)&v)[r]);
            denom += G;
            const int lab = (int)labf[c];
            #pragma unroll
            for (int q = 0; q < NK; ++q) numer[q] += (q == lab) ? G : 0.f;
            if (G > gmax) { gmax = G; gidx = c; }   // strict > keeps first index
        }
    }

    #pragma unroll
    for (int off = 32; off > 0; off >>= 1) {
        const float og = __shfl_down(gmax, off);
        const int   oi = __shfl_down(gidx, off);
        if (og > gmax || (og == gmax && oi < gidx)) { gmax = og; gidx = oi; }
        denom += __shfl_down(denom, off);
        #pragma unroll
        for (int q = 0; q < NK; ++q) numer[q] += __shfl_down(numer[q], off);
    }

    if (l == 0) {
        const float inv = 1.0f / (denom + 1e-12f);
        float best = -1.f; int pk = 0;
        #pragma unroll
        for (int q = 0; q < NK; ++q) {
            const float sc = numer[q] * inv;
            out[(size_t)s * NK + q] = sc;
            if (sc > best) { best = sc; pk = q; }
        }
        out[(size_t)NS * NK + s]      = (float)pk;    // pred
        out[(size_t)NS * NK + NS + s] = (float)gidx;  // clusters
    }
}

extern "C" void kernel_launch(void* const* d_in, const int* in_sizes, int n_in,
                              void* d_out, int out_size, void* d_ws, size_t ws_size,
                              hipStream_t stream)
{
    const float* data = (const float*)d_in[0];
    const float* n    = (const float*)d_in[2];
    const float* mu   = (const float*)d_in[3];
    const float* S    = (const float*)d_in[4];
    const int*   clab = (const int*)d_in[5];

    char* w = (char*)d_ws;
    int2* edt = (int2*)(w);                                     //     17,408 B
    unsigned short* Bph = (unsigned short*)(w + 35651584);      //  2,228,224 B
    unsigned short* Bpl = (unsigned short*)(w + 37879808);      //  2,228,224 B
    float* d2   = (float*)(w + 40108032);                       //  8,388,608 B
    float* labf = (float*)(w + 48496640);                       //      2,048 B

    hipLaunchKernelGGL(table_kernel, dim3(1), dim3(64), 0, stream, edt);
    hipLaunchKernelGGL(prep_kernel,  dim3(NC + ZB), dim3(256), 0, stream,
                       S, n, mu, clab, edt, Bph, Bpl, d2, labf);
    hipLaunchKernelGGL(gemm_kernel,  dim3(NS / 64, NC / 256, KSPLIT), dim3(256), 0, stream,
                       data, edt, Bph, Bpl, d2);
    hipLaunchKernelGGL(score_kernel, dim3(NS / 4), dim3(256), 0, stream,
                       d2, labf, (float*)d_out);
}

// Round 2
// 154.010 us; speedup vs baseline: 1.1883x; 1.0018x over previous
//
#include <hip/hip_runtime.h>
#include <hip/hip_bf16.h>
#include <math.h>

#define NS 4096      // samples
#define NC 512       // clusters
#define ND 64        // feature dim
#define NK 10        // classes
#define NPAIR 2080   // upper-triangle pairs (e<=d) of 64x64
#define KP 2176      // 2080 + 64 (linear) + 1 (const) + 31 zero-pad; 68*32
#define BOFF 2080
#define KOFF 2144
#define KSPLIT 4
#define KT_PER (KP / 32 / KSPLIT)   // 17 k-chunks per split block
#define ZB 1024                     // d2-zeroing blocks
#define QB 2048                     // Q-precompute blocks (2 rows each)

typedef __attribute__((ext_vector_type(8))) short short8;
typedef __attribute__((ext_vector_type(4))) float floatx4;

__device__ inline unsigned short f2b(float x) {
    __hip_bfloat16 h = __float2bfloat16(x);           // RNE
    return __builtin_bit_cast(unsigned short, h);
}
__device__ inline float b2f(unsigned short u) {
    __hip_bfloat16 h = __builtin_bit_cast(__hip_bfloat16, u);
    return __bfloat162float(h);
}

// true v_readlane_b32 (lane is a compile-time literal at every use site)
__device__ inline float rlane(float v, int k) {
    return __builtin_bit_cast(float, __builtin_amdgcn_readlane(__builtin_bit_cast(int, v), k));
}

// async global->LDS, 16B per lane (m97 lever); dst = wave-uniform base + lane*16
__device__ inline void gl16(const void* g, void* l) {
    __builtin_amdgcn_global_load_lds(
        (const __attribute__((address_space(1))) unsigned int*)g,
        (__attribute__((address_space(3))) unsigned int*)l, 16, 0, 0);
}

// ---------------- (e,d) table with sentinels: val[p] = z[e]*z[d] ------------
__global__ void table_kernel(uchar2* __restrict__ edt) {
    const int e = threadIdx.x;                        // 64 threads
    int off = e * 64 - (e * (e - 1)) / 2;             // row e starts here
    for (int d = e; d < 64; ++d) edt[off + d - e] = make_uchar2(e, d);
    edt[BOFF + e] = make_uchar2(e, 64);               // linear terms: z*1
    if (e == 0) edt[KOFF] = make_uchar2(64, 64);      // const term: 1
    if (e < KP - KOFF - 1) edt[KOFF + 1 + e] = make_uchar2(65, 65);   // pad: 0
}

// ---------------- prep: 3 roles ---------------------------------------------
//  role A (blk <  NC):            Sigma^-1 (4-wave coop GJ) + beta pack
//  role B (NC <= blk < NC+ZB):    d2 zeroing
//  role C (blk >= NC+ZB):         Q precompute (R17): Qh/Ql[4096][2176] bf16
//     hi/lo pair products. Moves gemm's per-kt A-build (VALU + scalar zS LDS
//     reads + 4B AhS stores -- the real SQ_LDS_BANK_CONFLICT source, proven by
//     R1's no-op swizzle) into a memory-bound role that overlaps roles A/B.
//     v = z[e]*z[d] is the bit-identical expression gemm used -> absmax 0.
__global__ __launch_bounds__(256, 4) void prep_kernel(
    const float* __restrict__ data, const float* __restrict__ S,
    const float* __restrict__ n, const float* __restrict__ mu,
    const int* __restrict__ clab, const uchar2* __restrict__ edt,
    unsigned short* __restrict__ Qh, unsigned short* __restrict__ Ql,
    unsigned short* __restrict__ Bph, unsigned short* __restrict__ Bpl,
    float* __restrict__ d2, float* __restrict__ labf)
{
    __shared__ float AcolS[ND * (ND + 1)];            // Sinv mirror [64][65]
    __shared__ float cbuf[ND];                        // bvec staging
    __shared__ float rowbuf[2][ND];                   // GJ pivot-row broadcast
    __shared__ float kksS[1];
    __shared__ float zq[2][66];                       // Q-role rows + sentinels

    if (blockIdx.x >= NC + ZB) {                      // ---- role C: Q build --
        const int qb = blockIdx.x - (NC + ZB);        // 0..QB-1
        const int half = threadIdx.x >> 7;            // 2 rows per block
        const int i = threadIdx.x & 127;              // 2 waves per row
        const int row = qb * 2 + half;
        if (i < 64) zq[half][i] = data[(size_t)row * ND + i];
        else if (i == 64) { zq[half][64] = 1.0f; zq[half][65] = 0.0f; }
        __syncthreads();
        const float* __restrict__ zr = zq[half];
        unsigned short* __restrict__ qh = Qh + (size_t)row * KP;
        unsigned short* __restrict__ ql = Ql + (size_t)row * KP;
        #pragma unroll
        for (int t = 0; t < 17; ++t) {                // 17*128 = 2176
            const int p = t * 128 + i;
            const uchar2 ed = edt[p];
            const float v = zr[ed.x] * zr[ed.y];
            const unsigned short h = f2b(v);
            const unsigned short l = f2b(v - b2f(h));
            qh[p] = h;
            ql[p] = l;
        }
        return;
    }

    if (blockIdx.x >= NC) {                           // ---- role B: d2 zero --
        const size_t base = (size_t)(blockIdx.x - NC) * 2048 + threadIdx.x * 8;
        *(float4*)&d2[base]     = make_float4(0.f, 0.f, 0.f, 0.f);
        *(float4*)&d2[base + 4] = make_float4(0.f, 0.f, 0.f, 0.f);
        return;
    }

    // ---- role A: 4-wave cooperative Gauss-Jordan (R16) ----
    const int c = blockIdx.x;
    const int tid = threadIdx.x;
    const int j = tid & 63;                           // column owned by lane
    const int w = tid >> 6;                           // wave -> rows 16w..16w+15
    const int rbase = w * 16;

    const float inv_nc = 1.0f / n[c];
    const float* __restrict__ Sc = S + (size_t)c * ND * ND + j;

    float4 B0, B1, B2, B3;
#define LOADR(u) {                                                   \
    const float x0 = Sc[(rbase + 4*(u) + 0) * ND] * inv_nc;          \
    const float x1 = Sc[(rbase + 4*(u) + 1) * ND] * inv_nc;          \
    const float x2 = Sc[(rbase + 4*(u) + 2) * ND] * inv_nc;          \
    const float x3 = Sc[(rbase + 4*(u) + 3) * ND] * inv_nc;          \
    B##u.x = (rbase + 4*(u) + 0 == j) ? x0 + 1e-6f : x0;             \
    B##u.y = (rbase + 4*(u) + 1 == j) ? x1 + 1e-6f : x1;             \
    B##u.z = (rbase + 4*(u) + 2 == j) ? x2 + 1e-6f : x2;             \
    B##u.w = (rbase + 4*(u) + 3 == j) ? x3 + 1e-6f : x3; }
    LOADR(0) LOADR(1) LOADR(2) LOADR(3)
#undef LOADR

#define UPD4(u, K) {                                                  \
    const float c0 = rlane(B##u.x, K);                                \
    const float c1 = rlane(B##u.y, K);                                \
    const float c2 = rlane(B##u.z, K);                                \
    const float c3 = rlane(B##u.w, K);                                \
    B##u.x = (om && (4*(u)+0 == ((K)&15))) ? rowk : B##u.x * am - c0 * rowk; \
    B##u.y = (om && (4*(u)+1 == ((K)&15))) ? rowk : B##u.y * am - c1 * rowk; \
    B##u.z = (om && (4*(u)+2 == ((K)&15))) ? rowk : B##u.z * am - c2 * rowk; \
    B##u.w = (om && (4*(u)+3 == ((K)&15))) ? rowk : B##u.w * am - c3 * rowk; \
}
#define STEPC(TL, C, K) {                                             \
    if (w == ((K) >> 4)) {                                            \
        const float rp = B##TL.C;         /* M[k][j]: own register */ \
        const float pv = rlane(rp, K);    /* pivot M[k][k] */         \
        const float ip = 1.0f / pv;                                   \
        rowbuf[(K) & 1][j] = (j == (K)) ? ip : rp * ip;               \
    }                                                                 \
    __syncthreads();                                                  \
    const float rowk = rowbuf[(K) & 1][j];                            \
    const float am = (j == (K)) ? 0.0f : 1.0f;                        \
    const bool om = (w == ((K) >> 4));                                \
    UPD4(0, K) UPD4(1, K) UPD4(2, K) UPD4(3, K)                       \
}
#define STEP4(T, TL) STEPC(TL, x, 4*(T)+0) STEPC(TL, y, 4*(T)+1) \
                     STEPC(TL, z, 4*(T)+2) STEPC(TL, w, 4*(T)+3)
#define FOR16P(M) M(0,0) M(1,1) M(2,2) M(3,3) M(4,0) M(5,1) M(6,2) M(7,3) \
                  M(8,0) M(9,1) M(10,2) M(11,3) M(12,0) M(13,1) M(14,2) M(15,3)
    FOR16P(STEP4)
#undef FOR16P
#undef STEP4
#undef STEPC
#undef UPD4

    // mirror Sinv into LDS for the pack gather (all 4 waves, disjoint rows)
#define MIR(u) *(float4*)&AcolS[j * (ND + 1) + rbase + 4*(u)] = B##u;
    MIR(0) MIR(1) MIR(2) MIR(3)
#undef MIR
    __syncthreads();                                  // AcolS complete

    if (w == 0) {                                     // y = Sinv*mu, kk, labels
        const float* __restrict__ muc = mu + (size_t)c * ND;
        float y = 0.f;
        #pragma unroll
        for (int t = 0; t < 16; ++t) {
            const float4 v = *(const float4*)&AcolS[j * (ND + 1) + 4 * t];
            y += v.x * muc[4*t]     + v.y * muc[4*t + 1]
               + v.z * muc[4*t + 2] + v.w * muc[4*t + 3];
        }
        cbuf[j] = -2.0f * y;                          // bvec values
        float kk = muc[j] * y;
        #pragma unroll
        for (int off = 32; off > 0; off >>= 1) kk += __shfl_down(kk, off);
        if (j == 0) {
            kksS[0] = kk;
            int lab = 0;
            for (int q = 0; q < NK; ++q) if (clab[c * NK + q] != 0) lab = q;
            labf[c] = (float)lab;
        }
    }
    __syncthreads();
    const float kks = kksS[0];

    unsigned short* __restrict__ ph = Bph + (size_t)c * KP;
    unsigned short* __restrict__ pl = Bpl + (size_t)c * KP;
    #pragma unroll
    for (int i = 0; i < 9; ++i) {                     // 34 iters split 4 ways
        const int t = w + 4 * i;
        if (t < KP / 64) {
            const int p = t * 64 + j;
            float val;
            if (p < NPAIR) {
                const uchar2 ed = edt[p];
                val = (ed.x == ed.y) ? AcolS[ed.x * (ND + 1) + ed.x]
                    : (AcolS[ed.y * (ND + 1) + ed.x] + AcolS[ed.x * (ND + 1) + ed.y]);
            } else if (p < KOFF) val = cbuf[p - BOFF];
            else if (p == KOFF)  val = kks;
            else                 val = 0.f;
            const unsigned short h = f2b(val);
            const unsigned short l = f2b(val - b2f(h));
            ph[p] = h;
            pl[p] = l;
        }
    }
}

// ---------------- d2 = Q·Beta^T, pure GEMM, 1-deep pipelined ----------------
// R17: A precomputed (role C) -> no per-kt A-build. Per kt: ds_read frags(cur),
// issue 10 gl16 for kt+1 into buf^1, 48 MFMA, ONE __syncthreads. The barrier's
// vmcnt(0) drain now sits AFTER the MFMA block, so staging latency hides under
// MFMA issue (guide §5.5 T3 minimum recipe; race-free with one barrier: buf^1
// was last ds_read in kt-1, completed before the kt-1 barrier every wave passed
// before issuing kt's stage). LDS 80KB -> exactly 2 blocks/CU.
// XOR swizzle (T2, rule 21): LDS[row][slot] holds global seg slot^((row>>2)&3),
// staged via pre-swizzled GLOBAL source (gl16 dst stays linear), read back with
// slot quad^((rlo>>2)&3) -- involution, bits unchanged, d2 bit-identical.
__global__ __launch_bounds__(256, 2) void gemm_kernel(
    const unsigned short* __restrict__ Qh, const unsigned short* __restrict__ Ql,
    const unsigned short* __restrict__ Bph, const unsigned short* __restrict__ Bpl,
    float* __restrict__ d2)
{
    __shared__ unsigned short AhS[2][64 * 32], AlS[2][64 * 32];   // 16KB
    __shared__ unsigned short BhS[2][256 * 32], BlS[2][256 * 32]; // 64KB

    const int tid  = threadIdx.x;
    const int lane = tid & 63, w = tid >> 6;
    const int quad = lane >> 4, rlo = lane & 15;
    const int m0 = blockIdx.x * 64;      // sample tile
    const int n0 = blockIdx.y * 256;     // cluster tile
    const int koff0 = blockIdx.z * KT_PER * 32;   // this block's K-slice start

    // staging: thread -> LDS row tid>>2, slot tid&3 (dst linear = tid*16B);
    // source segment pre-swizzled so LDS[row][slot] = global seg slot^((row>>2)&3)
    const int srow = tid >> 2;
    const int sswz = (tid & 3) ^ ((srow >> 2) & 3);
    const unsigned short* aGh = Qh + (size_t)(m0 + srow) * KP + koff0 + sswz * 8;
    const unsigned short* aGl = Ql + (size_t)(m0 + srow) * KP + koff0 + sswz * 8;
    const unsigned short* bGh[4];
    const unsigned short* bGl[4];
    #pragma unroll
    for (int rd = 0; rd < 4; ++rd) {
        const size_t off = (size_t)(n0 + rd * 64 + srow) * KP + koff0 + sswz * 8;
        bGh[rd] = Bph + off;
        bGl[rd] = Bpl + off;
    }
    const int swz8 = (quad ^ ((rlo >> 2) & 3)) * 8;   // read-side slot

    floatx4 acc[4][4] = {};

    // prologue: stage tile 0 into buf 0
    gl16(aGh, &AhS[0][tid * 8]);
    gl16(aGl, &AlS[0][tid * 8]);
    #pragma unroll
    for (int rd = 0; rd < 4; ++rd) {
        gl16(bGh[rd], &BhS[0][(rd * 256 + tid) * 8]);
        gl16(bGl[rd], &BlS[0][(rd * 256 + tid) * 8]);
    }
    __syncthreads();                                  // tile 0 resident

    int cur = 0;
    for (int kt = 0; kt < KT_PER; ++kt) {
        // issue next tile's staging first (max in-flight time under MFMA)
        if (kt + 1 < KT_PER) {
            const int ko = (kt + 1) * 32;
            gl16(aGh + ko, &AhS[cur ^ 1][tid * 8]);
            gl16(aGl + ko, &AlS[cur ^ 1][tid * 8]);
            #pragma unroll
            for (int rd = 0; rd < 4; ++rd) {
                gl16(bGh[rd] + ko, &BhS[cur ^ 1][(rd * 256 + tid) * 8]);
                gl16(bGl[rd] + ko, &BlS[cur ^ 1][(rd * 256 + tid) * 8]);
            }
        }

        short8 ah[4], al[4], bh[4], bl[4];
        #pragma unroll
        for (int i = 0; i < 4; ++i) {
            ah[i] = *(const short8*)&AhS[cur][(i * 16 + rlo) * 32 + swz8];
            al[i] = *(const short8*)&AlS[cur][(i * 16 + rlo) * 32 + swz8];
        }
        #pragma unroll
        for (int j2 = 0; j2 < 4; ++j2) {
            const int r = w * 64 + j2 * 16 + rlo;
            bh[j2] = *(const short8*)&BhS[cur][r * 32 + swz8];
            bl[j2] = *(const short8*)&BlS[cur][r * 32 + swz8];
        }

        #pragma unroll
        for (int i = 0; i < 4; ++i)
            #pragma unroll
            for (int j2 = 0; j2 < 4; ++j2) {
                acc[i][j2] = __builtin_amdgcn_mfma_f32_16x16x32_bf16(al[i], bh[j2], acc[i][j2], 0, 0, 0);
                acc[i][j2] = __builtin_amdgcn_mfma_f32_16x16x32_bf16(ah[i], bl[j2], acc[i][j2], 0, 0, 0);
                acc[i][j2] = __builtin_amdgcn_mfma_f32_16x16x32_bf16(ah[i], bh[j2], acc[i][j2], 0, 0, 0);
            }

        __syncthreads();   // drains vmcnt(0): next tile landed; cur free to overwrite
        cur ^= 1;
    }

    // C layout (verified m89): col = lane&15, row = (lane>>4)*4 + reg
    #pragma unroll
    for (int i = 0; i < 4; ++i)
        #pragma unroll
        for (int j2 = 0; j2 < 4; ++j2) {
            const int m = m0 + i * 16 + quad * 4;
            const int nn = n0 + w * 64 + j2 * 16 + rlo;
            #pragma unroll
            for (int r = 0; r < 4; ++r)
                atomicAdd(&d2[(size_t)(m + r) * NC + nn], acc[i][j2][r]);
        }
}

// ---------------- scores / argmaxes: 4 waves/block, one sample per wave -----
__global__ __launch_bounds__(256) void score_kernel(
    const float* __restrict__ d2, const float* __restrict__ labf,
    float* __restrict__ out)
{
    const int s = blockIdx.x * 4 + (threadIdx.x >> 6);
    const int l = threadIdx.x & 63;

    float numer[NK];
    #pragma unroll
    for (int q = 0; q < NK; ++q) numer[q] = 0.f;
    float denom = 0.f, gmax = -1.f;
    int gidx = 0;

    #pragma unroll
    for (int i = 0; i < NC / 256; ++i) {         // float4 per lane, index-ascending
        const int c0 = i * 256 + l * 4;
        const float4 v = *(const float4*)&d2[(size_t)s * NC + c0];
        #pragma unroll
        for (int r = 0; r < 4; ++r) {
            const int c = c0 + r;
            const float G = __expf(-0.5f * ((const float*)&v)[r]);
            denom += G;
            const int lab = (int)labf[c];
            #pragma unroll
            for (int q = 0; q < NK; ++q) numer[q] += (q == lab) ? G : 0.f;
            if (G > gmax) { gmax = G; gidx = c; }   // strict > keeps first index
        }
    }

    #pragma unroll
    for (int off = 32; off > 0; off >>= 1) {
        const float og = __shfl_down(gmax, off);
        const int   oi = __shfl_down(gidx, off);
        if (og > gmax || (og == gmax && oi < gidx)) { gmax = og; gidx = oi; }
        denom += __shfl_down(denom, off);
        #pragma unroll
        for (int q = 0; q < NK; ++q) numer[q] += __shfl_down(numer[q], off);
    }

    if (l == 0) {
        const float inv = 1.0f / (denom + 1e-12f);
        float best = -1.f; int pk = 0;
        #pragma unroll
        for (int q = 0; q < NK; ++q) {
            const float sc = numer[q] * inv;
            out[(size_t)s * NK + q] = sc;
            if (sc > best) { best = sc; pk = q; }
        }
        out[(size_t)NS * NK + s]      = (float)pk;    // pred
        out[(size_t)NS * NK + NS + s] = (float)gidx;  // clusters
    }
}

extern "C" void kernel_launch(void* const* d_in, const int* in_sizes, int n_in,
                              void* d_out, int out_size, void* d_ws, size_t ws_size,
                              hipStream_t stream)
{
    const float* data = (const float*)d_in[0];
    const float* n    = (const float*)d_in[2];
    const float* mu   = (const float*)d_in[3];
    const float* S    = (const float*)d_in[4];
    const int*   clab = (const int*)d_in[5];

    char* w = (char*)d_ws;
    unsigned short* Qh  = (unsigned short*)(w);                 // 17,825,792 B
    unsigned short* Ql  = (unsigned short*)(w + 17825792);      // 17,825,792 B
    unsigned short* Bph = (unsigned short*)(w + 35651584);      //  2,228,224 B
    unsigned short* Bpl = (unsigned short*)(w + 37879808);      //  2,228,224 B
    float* d2   = (float*)(w + 40108032);                       //  8,388,608 B
    float* labf = (float*)(w + 48496640);                       //      2,048 B
    uchar2* edt = (uchar2*)(w + 48498688);                      //      4,352 B

    hipLaunchKernelGGL(table_kernel, dim3(1), dim3(64), 0, stream, edt);
    hipLaunchKernelGGL(prep_kernel,  dim3(NC + ZB + QB), dim3(256), 0, stream,
                       data, S, n, mu, clab, edt, Qh, Ql, Bph, Bpl, d2, labf);
    hipLaunchKernelGGL(gemm_kernel,  dim3(NS / 64, NC / 256, KSPLIT), dim3(256), 0, stream,
                       Qh, Ql, Bph, Bpl, d2);
    hipLaunchKernelGGL(score_kernel, dim3(NS / 4), dim3(256), 0, stream,
                       d2, labf, (float*)d_out);
}

// Round 3
// 150.987 us; speedup vs baseline: 1.2121x; 1.0200x over previous
//
#include <hip/hip_runtime.h>
#include <hip/hip_bf16.h>
#include <math.h>

#define NS 4096      // samples
#define NC 512       // clusters
#define ND 64        // feature dim
#define NK 10        // classes
#define NPAIR 2080   // upper-triangle pairs (e<=d) of 64x64
#define KP 2176      // 2080 + 64 (linear) + 1 (const) + 31 zero-pad; 68*32
#define BOFF 2080
#define KOFF 2144
#define KSPLIT 4
#define KT_PER (KP / 32 / KSPLIT)   // 17 k-chunks per split block
#define ZB 1024                     // d2-zeroing blocks
#define QB 2048                     // Q-precompute blocks (2 rows each)

typedef __attribute__((ext_vector_type(8))) short short8;
typedef __attribute__((ext_vector_type(4))) float floatx4;

__device__ inline unsigned short f2b(float x) {
    __hip_bfloat16 h = __float2bfloat16(x);           // RNE
    return __builtin_bit_cast(unsigned short, h);
}
__device__ inline float b2f(unsigned short u) {
    __hip_bfloat16 h = __builtin_bit_cast(__hip_bfloat16, u);
    return __bfloat162float(h);
}

// true v_readlane_b32 (lane is a compile-time literal at every use site)
__device__ inline float rlane(float v, int k) {
    return __builtin_bit_cast(float, __builtin_amdgcn_readlane(__builtin_bit_cast(int, v), k));
}

// async global->LDS, 16B per lane (m97 lever); dst = wave-uniform base + lane*16
__device__ inline void gl16(const void* g, void* l) {
    __builtin_amdgcn_global_load_lds(
        (const __attribute__((address_space(1))) unsigned int*)g,
        (__attribute__((address_space(3))) unsigned int*)l, 16, 0, 0);
}

// ---------------- (e,d) table with sentinels: val[p] = z[e]*z[d] ------------
__global__ void table_kernel(uchar2* __restrict__ edt) {
    const int e = threadIdx.x;                        // 64 threads
    int off = e * 64 - (e * (e - 1)) / 2;             // row e starts here
    for (int d = e; d < 64; ++d) edt[off + d - e] = make_uchar2(e, d);
    edt[BOFF + e] = make_uchar2(e, 64);               // linear terms: z*1
    if (e == 0) edt[KOFF] = make_uchar2(64, 64);      // const term: 1
    if (e < KP - KOFF - 1) edt[KOFF + 1 + e] = make_uchar2(65, 65);   // pad: 0
}

// ---------------- prep: 3 roles ---------------------------------------------
//  role A (blk <  NC):            Sigma^-1 (4-wave coop GJ) + beta pack
//  role B (NC <= blk < NC+ZB):    d2 zeroing
//  role C (blk >= NC+ZB):         Q precompute: Qh/Ql[4096][2176] bf16 hi/lo
//     pair products (bit-identical expression to the old in-gemm A-build).
__global__ __launch_bounds__(256, 4) void prep_kernel(
    const float* __restrict__ data, const float* __restrict__ S,
    const float* __restrict__ n, const float* __restrict__ mu,
    const int* __restrict__ clab, const uchar2* __restrict__ edt,
    unsigned short* __restrict__ Qh, unsigned short* __restrict__ Ql,
    unsigned short* __restrict__ Bph, unsigned short* __restrict__ Bpl,
    float* __restrict__ d2, float* __restrict__ labf)
{
    __shared__ float AcolS[ND * (ND + 1)];            // Sinv mirror [64][65]
    __shared__ float cbuf[ND];                        // bvec staging
    __shared__ float rowbuf[2][ND];                   // GJ pivot-row broadcast
    __shared__ float kksS[1];
    __shared__ float zq[2][66];                       // Q-role rows + sentinels

    if (blockIdx.x >= NC + ZB) {                      // ---- role C: Q build --
        const int qb = blockIdx.x - (NC + ZB);        // 0..QB-1
        const int half = threadIdx.x >> 7;            // 2 rows per block
        const int i = threadIdx.x & 127;              // 2 waves per row
        const int row = qb * 2 + half;
        if (i < 64) zq[half][i] = data[(size_t)row * ND + i];
        else if (i == 64) { zq[half][64] = 1.0f; zq[half][65] = 0.0f; }
        __syncthreads();
        const float* __restrict__ zr = zq[half];
        unsigned short* __restrict__ qh = Qh + (size_t)row * KP;
        unsigned short* __restrict__ ql = Ql + (size_t)row * KP;
        #pragma unroll
        for (int t = 0; t < 17; ++t) {                // 17*128 = 2176
            const int p = t * 128 + i;
            const uchar2 ed = edt[p];
            const float v = zr[ed.x] * zr[ed.y];
            const unsigned short h = f2b(v);
            const unsigned short l = f2b(v - b2f(h));
            qh[p] = h;
            ql[p] = l;
        }
        return;
    }

    if (blockIdx.x >= NC) {                           // ---- role B: d2 zero --
        const size_t base = (size_t)(blockIdx.x - NC) * 2048 + threadIdx.x * 8;
        *(float4*)&d2[base]     = make_float4(0.f, 0.f, 0.f, 0.f);
        *(float4*)&d2[base + 4] = make_float4(0.f, 0.f, 0.f, 0.f);
        return;
    }

    // ---- role A: 4-wave cooperative Gauss-Jordan (R16) ----
    const int c = blockIdx.x;
    const int tid = threadIdx.x;
    const int j = tid & 63;                           // column owned by lane
    const int w = tid >> 6;                           // wave -> rows 16w..16w+15
    const int rbase = w * 16;

    const float inv_nc = 1.0f / n[c];
    const float* __restrict__ Sc = S + (size_t)c * ND * ND + j;

    float4 B0, B1, B2, B3;
#define LOADR(u) {                                                   \
    const float x0 = Sc[(rbase + 4*(u) + 0) * ND] * inv_nc;          \
    const float x1 = Sc[(rbase + 4*(u) + 1) * ND] * inv_nc;          \
    const float x2 = Sc[(rbase + 4*(u) + 2) * ND] * inv_nc;          \
    const float x3 = Sc[(rbase + 4*(u) + 3) * ND] * inv_nc;          \
    B##u.x = (rbase + 4*(u) + 0 == j) ? x0 + 1e-6f : x0;             \
    B##u.y = (rbase + 4*(u) + 1 == j) ? x1 + 1e-6f : x1;             \
    B##u.z = (rbase + 4*(u) + 2 == j) ? x2 + 1e-6f : x2;             \
    B##u.w = (rbase + 4*(u) + 3 == j) ? x3 + 1e-6f : x3; }
    LOADR(0) LOADR(1) LOADR(2) LOADR(3)
#undef LOADR

#define UPD4(u, K) {                                                  \
    const float c0 = rlane(B##u.x, K);                                \
    const float c1 = rlane(B##u.y, K);                                \
    const float c2 = rlane(B##u.z, K);                                \
    const float c3 = rlane(B##u.w, K);                                \
    B##u.x = (om && (4*(u)+0 == ((K)&15))) ? rowk : B##u.x * am - c0 * rowk; \
    B##u.y = (om && (4*(u)+1 == ((K)&15))) ? rowk : B##u.y * am - c1 * rowk; \
    B##u.z = (om && (4*(u)+2 == ((K)&15))) ? rowk : B##u.z * am - c2 * rowk; \
    B##u.w = (om && (4*(u)+3 == ((K)&15))) ? rowk : B##u.w * am - c3 * rowk; \
}
#define STEPC(TL, C, K) {                                             \
    if (w == ((K) >> 4)) {                                            \
        const float rp = B##TL.C;         /* M[k][j]: own register */ \
        const float pv = rlane(rp, K);    /* pivot M[k][k] */         \
        const float ip = 1.0f / pv;                                   \
        rowbuf[(K) & 1][j] = (j == (K)) ? ip : rp * ip;               \
    }                                                                 \
    __syncthreads();                                                  \
    const float rowk = rowbuf[(K) & 1][j];                            \
    const float am = (j == (K)) ? 0.0f : 1.0f;                        \
    const bool om = (w == ((K) >> 4));                                \
    UPD4(0, K) UPD4(1, K) UPD4(2, K) UPD4(3, K)                       \
}
#define STEP4(T, TL) STEPC(TL, x, 4*(T)+0) STEPC(TL, y, 4*(T)+1) \
                     STEPC(TL, z, 4*(T)+2) STEPC(TL, w, 4*(T)+3)
#define FOR16P(M) M(0,0) M(1,1) M(2,2) M(3,3) M(4,0) M(5,1) M(6,2) M(7,3) \
                  M(8,0) M(9,1) M(10,2) M(11,3) M(12,0) M(13,1) M(14,2) M(15,3)
    FOR16P(STEP4)
#undef FOR16P
#undef STEP4
#undef STEPC
#undef UPD4

    // mirror Sinv into LDS for the pack gather (all 4 waves, disjoint rows)
#define MIR(u) *(float4*)&AcolS[j * (ND + 1) + rbase + 4*(u)] = B##u;
    MIR(0) MIR(1) MIR(2) MIR(3)
#undef MIR
    __syncthreads();                                  // AcolS complete

    if (w == 0) {                                     // y = Sinv*mu, kk, labels
        const float* __restrict__ muc = mu + (size_t)c * ND;
        float y = 0.f;
        #pragma unroll
        for (int t = 0; t < 16; ++t) {
            const float4 v = *(const float4*)&AcolS[j * (ND + 1) + 4 * t];
            y += v.x * muc[4*t]     + v.y * muc[4*t + 1]
               + v.z * muc[4*t + 2] + v.w * muc[4*t + 3];
        }
        cbuf[j] = -2.0f * y;                          // bvec values
        float kk = muc[j] * y;
        #pragma unroll
        for (int off = 32; off > 0; off >>= 1) kk += __shfl_down(kk, off);
        if (j == 0) {
            kksS[0] = kk;
            int lab = 0;
            for (int q = 0; q < NK; ++q) if (clab[c * NK + q] != 0) lab = q;
            labf[c] = (float)lab;
        }
    }
    __syncthreads();
    const float kks = kksS[0];

    unsigned short* __restrict__ ph = Bph + (size_t)c * KP;
    unsigned short* __restrict__ pl = Bpl + (size_t)c * KP;
    #pragma unroll
    for (int i = 0; i < 9; ++i) {                     // 34 iters split 4 ways
        const int t = w + 4 * i;
        if (t < KP / 64) {
            const int p = t * 64 + j;
            float val;
            if (p < NPAIR) {
                const uchar2 ed = edt[p];
                val = (ed.x == ed.y) ? AcolS[ed.x * (ND + 1) + ed.x]
                    : (AcolS[ed.y * (ND + 1) + ed.x] + AcolS[ed.x * (ND + 1) + ed.y]);
            } else if (p < KOFF) val = cbuf[p - BOFF];
            else if (p == KOFF)  val = kks;
            else                 val = 0.f;
            const unsigned short h = f2b(val);
            const unsigned short l = f2b(val - b2f(h));
            ph[p] = h;
            pl[p] = l;
        }
    }
}

// ---------------- d2 = Q·Beta^T, T3+T4 counted-vmcnt pipeline ---------------
// R18: R2's __syncthreads after MFMA compiled to vmcnt(0) drain -> every kt
// stalled on HBM/L3-cold Q loads (~600-900cy > 460cy MFMA phase); counters:
// MfmaUtil 17.5 / VALU 8.8 / HBM 15% => ~65% wait. Now: raw s_barrier +
// counted vmcnt(10), 2-tile-deep ring over the 2 LDS buffers. Per kt:
//   frags <- buf[cur] (16 ds_read_b128)
//   lgkmcnt(0); sched_barrier; s_barrier     // all waves hold frags; cur free
//   STAGE(cur <- kt+2)                       // 10 gl16, overwrite safe
//   setprio(1) 48 MFMA setprio(0)            // T5: phase role-split exists now
//   vmcnt(10)                                // tile kt+1 landed; kt+2 IN FLIGHT
//   s_barrier
// Tail (kt >= KT_PER-2): no stage, vmcnt(0). Loads get ~2 phases to land.
// Frag/staging addressing byte-identical to R2 -> d2 bit-identical.
__global__ __launch_bounds__(256, 2) void gemm_kernel(
    const unsigned short* __restrict__ Qh, const unsigned short* __restrict__ Ql,
    const unsigned short* __restrict__ Bph, const unsigned short* __restrict__ Bpl,
    float* __restrict__ d2)
{
    __shared__ unsigned short AhS[2][64 * 32], AlS[2][64 * 32];   // 16KB
    __shared__ unsigned short BhS[2][256 * 32], BlS[2][256 * 32]; // 64KB

    const int tid  = threadIdx.x;
    const int lane = tid & 63, w = tid >> 6;
    const int quad = lane >> 4, rlo = lane & 15;
    const int m0 = blockIdx.x * 64;      // sample tile
    const int n0 = blockIdx.y * 256;     // cluster tile
    const int koff0 = blockIdx.z * KT_PER * 32;   // this block's K-slice start

    // staging: thread -> LDS row tid>>2, slot tid&3 (dst linear = tid*16B);
    // source segment pre-swizzled so LDS[row][slot] = global seg slot^((row>>2)&3)
    const int srow = tid >> 2;
    const int sswz = (tid & 3) ^ ((srow >> 2) & 3);
    const unsigned short* aGh = Qh + (size_t)(m0 + srow) * KP + koff0 + sswz * 8;
    const unsigned short* aGl = Ql + (size_t)(m0 + srow) * KP + koff0 + sswz * 8;
    const unsigned short* bGh[4];
    const unsigned short* bGl[4];
    #pragma unroll
    for (int rd = 0; rd < 4; ++rd) {
        const size_t off = (size_t)(n0 + rd * 64 + srow) * KP + koff0 + sswz * 8;
        bGh[rd] = Bph + off;
        bGl[rd] = Bpl + off;
    }
    const int swz8 = (quad ^ ((rlo >> 2) & 3)) * 8;   // read-side slot

    floatx4 acc[4][4] = {};

#define STAGE(b, t) {                                                 \
        const int _ko = (t) * 32;                                     \
        gl16(aGh + _ko, &AhS[b][tid * 8]);                            \
        gl16(aGl + _ko, &AlS[b][tid * 8]);                            \
        _Pragma("unroll")                                             \
        for (int rd = 0; rd < 4; ++rd) {                              \
            gl16(bGh[rd] + _ko, &BhS[b][(rd * 256 + tid) * 8]);       \
            gl16(bGl[rd] + _ko, &BlS[b][(rd * 256 + tid) * 8]);       \
        } }

    // prologue: tiles 0 and 1 in flight; wait only for tile 0
    STAGE(0, 0)
    STAGE(1, 1)
    asm volatile("s_waitcnt vmcnt(10)" ::: "memory");
    __builtin_amdgcn_s_barrier();

    for (int kt = 0; kt < KT_PER; ++kt) {
        const int cur = kt & 1;

        short8 ah[4], al[4], bh[4], bl[4];
        #pragma unroll
        for (int i = 0; i < 4; ++i) {
            ah[i] = *(const short8*)&AhS[cur][(i * 16 + rlo) * 32 + swz8];
            al[i] = *(const short8*)&AlS[cur][(i * 16 + rlo) * 32 + swz8];
        }
        #pragma unroll
        for (int j2 = 0; j2 < 4; ++j2) {
            const int r = w * 64 + j2 * 16 + rlo;
            bh[j2] = *(const short8*)&BhS[cur][r * 32 + swz8];
            bl[j2] = *(const short8*)&BlS[cur][r * 32 + swz8];
        }
        asm volatile("s_waitcnt lgkmcnt(0)" ::: "memory");
        __builtin_amdgcn_sched_barrier(0);
        __builtin_amdgcn_s_barrier();     // all waves hold frags; cur reusable

        if (kt < KT_PER - 2) STAGE(cur, kt + 2)

        __builtin_amdgcn_s_setprio(1);
        #pragma unroll
        for (int i = 0; i < 4; ++i)
            #pragma unroll
            for (int j2 = 0; j2 < 4; ++j2) {
                acc[i][j2] = __builtin_amdgcn_mfma_f32_16x16x32_bf16(al[i], bh[j2], acc[i][j2], 0, 0, 0);
                acc[i][j2] = __builtin_amdgcn_mfma_f32_16x16x32_bf16(ah[i], bl[j2], acc[i][j2], 0, 0, 0);
                acc[i][j2] = __builtin_amdgcn_mfma_f32_16x16x32_bf16(ah[i], bh[j2], acc[i][j2], 0, 0, 0);
            }
        __builtin_amdgcn_s_setprio(0);

        if (kt < KT_PER - 2) {
            asm volatile("s_waitcnt vmcnt(10)" ::: "memory");  // kt+1 landed
        } else {
            asm volatile("s_waitcnt vmcnt(0)" ::: "memory");   // tail drain
        }
        __builtin_amdgcn_s_barrier();
    }
#undef STAGE

    // C layout (verified m89): col = lane&15, row = (lane>>4)*4 + reg
    #pragma unroll
    for (int i = 0; i < 4; ++i)
        #pragma unroll
        for (int j2 = 0; j2 < 4; ++j2) {
            const int m = m0 + i * 16 + quad * 4;
            const int nn = n0 + w * 64 + j2 * 16 + rlo;
            #pragma unroll
            for (int r = 0; r < 4; ++r)
                atomicAdd(&d2[(size_t)(m + r) * NC + nn], acc[i][j2][r]);
        }
}

// ---------------- scores / argmaxes: 4 waves/block, one sample per wave -----
__global__ __launch_bounds__(256) void score_kernel(
    const float* __restrict__ d2, const float* __restrict__ labf,
    float* __restrict__ out)
{
    const int s = blockIdx.x * 4 + (threadIdx.x >> 6);
    const int l = threadIdx.x & 63;

    float numer[NK];
    #pragma unroll
    for (int q = 0; q < NK; ++q) numer[q] = 0.f;
    float denom = 0.f, gmax = -1.f;
    int gidx = 0;

    #pragma unroll
    for (int i = 0; i < NC / 256; ++i) {         // float4 per lane, index-ascending
        const int c0 = i * 256 + l * 4;
        const float4 v = *(const float4*)&d2[(size_t)s * NC + c0];
        #pragma unroll
        for (int r = 0; r < 4; ++r) {
            const int c = c0 + r;
            const float G = __expf(-0.5f * ((const float*)&v)[r]);
            denom += G;
            const int lab = (int)labf[c];
            #pragma unroll
            for (int q = 0; q < NK; ++q) numer[q] += (q == lab) ? G : 0.f;
            if (G > gmax) { gmax = G; gidx = c; }   // strict > keeps first index
        }
    }

    #pragma unroll
    for (int off = 32; off > 0; off >>= 1) {
        const float og = __shfl_down(gmax, off);
        const int   oi = __shfl_down(gidx, off);
        if (og > gmax || (og == gmax && oi < gidx)) { gmax = og; gidx = oi; }
        denom += __shfl_down(denom, off);
        #pragma unroll
        for (int q = 0; q < NK; ++q) numer[q] += __shfl_down(numer[q], off);
    }

    if (l == 0) {
        const float inv = 1.0f / (denom + 1e-12f);
        float best = -1.f; int pk = 0;
        #pragma unroll
        for (int q = 0; q < NK; ++q) {
            const float sc = numer[q] * inv;
            out[(size_t)s * NK + q] = sc;
            if (sc > best) { best = sc; pk = q; }
        }
        out[(size_t)NS * NK + s]      = (float)pk;    // pred
        out[(size_t)NS * NK + NS + s] = (float)gidx;  // clusters
    }
}

extern "C" void kernel_launch(void* const* d_in, const int* in_sizes, int n_in,
                              void* d_out, int out_size, void* d_ws, size_t ws_size,
                              hipStream_t stream)
{
    const float* data = (const float*)d_in[0];
    const float* n    = (const float*)d_in[2];
    const float* mu   = (const float*)d_in[3];
    const float* S    = (const float*)d_in[4];
    const int*   clab = (const int*)d_in[5];

    char* w = (char*)d_ws;
    unsigned short* Qh  = (unsigned short*)(w);                 // 17,825,792 B
    unsigned short* Ql  = (unsigned short*)(w + 17825792);      // 17,825,792 B
    unsigned short* Bph = (unsigned short*)(w + 35651584);      //  2,228,224 B
    unsigned short* Bpl = (unsigned short*)(w + 37879808);      //  2,228,224 B
    float* d2   = (float*)(w + 40108032);                       //  8,388,608 B
    float* labf = (float*)(w + 48496640);                       //      2,048 B
    uchar2* edt = (uchar2*)(w + 48498688);                      //      4,352 B

    hipLaunchKernelGGL(table_kernel, dim3(1), dim3(64), 0, stream, edt);
    hipLaunchKernelGGL(prep_kernel,  dim3(NC + ZB + QB), dim3(256), 0, stream,
                       data, S, n, mu, clab, edt, Qh, Ql, Bph, Bpl, d2, labf);
    hipLaunchKernelGGL(gemm_kernel,  dim3(NS / 64, NC / 256, KSPLIT), dim3(256), 0, stream,
                       Qh, Ql, Bph, Bpl, d2);
    hipLaunchKernelGGL(score_kernel, dim3(NS / 4), dim3(256), 0, stream,
                       d2, labf, (float*)d_out);
}

// Round 4
// 150.676 us; speedup vs baseline: 1.2146x; 1.0021x over previous
//
#include <hip/hip_runtime.h>
#include <hip/hip_bf16.h>
#include <math.h>

#define NS 4096      // samples
#define NC 512       // clusters
#define ND 64        // feature dim
#define NK 10        // classes
#define NPAIR 2080   // upper-triangle pairs (e<=d) of 64x64
#define KP 2176      // 2080 + 64 (linear) + 1 (const) + 31 zero-pad; 68*32
#define BOFF 2080
#define KOFF 2144
#define KSPLIT 4
#define KT_PER (KP / 32 / KSPLIT)   // 17 k-chunks per split block
#define ZB 1024                     // d2-zeroing blocks
#define QB 2048                     // Q-precompute blocks (2 rows each)

typedef __attribute__((ext_vector_type(8))) short short8;
typedef __attribute__((ext_vector_type(4))) float floatx4;

__device__ inline unsigned short f2b(float x) {
    __hip_bfloat16 h = __float2bfloat16(x);           // RNE
    return __builtin_bit_cast(unsigned short, h);
}
__device__ inline float b2f(unsigned short u) {
    __hip_bfloat16 h = __builtin_bit_cast(__hip_bfloat16, u);
    return __bfloat162float(h);
}

// true v_readlane_b32 (lane is a compile-time literal at every use site)
__device__ inline float rlane(float v, int k) {
    return __builtin_bit_cast(float, __builtin_amdgcn_readlane(__builtin_bit_cast(int, v), k));
}

// async global->LDS, 16B per lane (m97 lever); dst = wave-uniform base + lane*16
__device__ inline void gl16(const void* g, void* l) {
    __builtin_amdgcn_global_load_lds(
        (const __attribute__((address_space(1))) unsigned int*)g,
        (__attribute__((address_space(3))) unsigned int*)l, 16, 0, 0);
}

// ---------------- (e,d) table with sentinels: val[p] = z[e]*z[d] ------------
__global__ void table_kernel(uchar2* __restrict__ edt) {
    const int e = threadIdx.x;                        // 64 threads
    int off = e * 64 - (e * (e - 1)) / 2;             // row e starts here
    for (int d = e; d < 64; ++d) edt[off + d - e] = make_uchar2(e, d);
    edt[BOFF + e] = make_uchar2(e, 64);               // linear terms: z*1
    if (e == 0) edt[KOFF] = make_uchar2(64, 64);      // const term: 1
    if (e < KP - KOFF - 1) edt[KOFF + 1 + e] = make_uchar2(65, 65);   // pad: 0
}

// ---------------- prep: 3 roles ---------------------------------------------
//  role A (blk <  NC):            Sigma^-1 (4-wave coop GJ) + beta pack
//  role B (NC <= blk < NC+ZB):    d2 zeroing
//  role C (blk >= NC+ZB):         Q precompute: Qh/Ql[4096][2176] bf16 hi/lo
//     pair products (bit-identical expression to the old in-gemm A-build).
__global__ __launch_bounds__(256, 4) void prep_kernel(
    const float* __restrict__ data, const float* __restrict__ S,
    const float* __restrict__ n, const float* __restrict__ mu,
    const int* __restrict__ clab, const uchar2* __restrict__ edt,
    unsigned short* __restrict__ Qh, unsigned short* __restrict__ Ql,
    unsigned short* __restrict__ Bph, unsigned short* __restrict__ Bpl,
    float* __restrict__ d2, float* __restrict__ labf)
{
    __shared__ float AcolS[ND * (ND + 1)];            // Sinv mirror [64][65]
    __shared__ float cbuf[ND];                        // bvec staging
    __shared__ float rowbuf[2][ND];                   // GJ pivot-row broadcast
    __shared__ float kksS[1];
    __shared__ float zq[2][66];                       // Q-role rows + sentinels

    if (blockIdx.x >= NC + ZB) {                      // ---- role C: Q build --
        const int qb = blockIdx.x - (NC + ZB);        // 0..QB-1
        const int half = threadIdx.x >> 7;            // 2 rows per block
        const int i = threadIdx.x & 127;              // 2 waves per row
        const int row = qb * 2 + half;
        if (i < 64) zq[half][i] = data[(size_t)row * ND + i];
        else if (i == 64) { zq[half][64] = 1.0f; zq[half][65] = 0.0f; }
        __syncthreads();
        const float* __restrict__ zr = zq[half];
        unsigned short* __restrict__ qh = Qh + (size_t)row * KP;
        unsigned short* __restrict__ ql = Ql + (size_t)row * KP;
        #pragma unroll
        for (int t = 0; t < 17; ++t) {                // 17*128 = 2176
            const int p = t * 128 + i;
            const uchar2 ed = edt[p];
            const float v = zr[ed.x] * zr[ed.y];
            const unsigned short h = f2b(v);
            const unsigned short l = f2b(v - b2f(h));
            qh[p] = h;
            ql[p] = l;
        }
        return;
    }

    if (blockIdx.x >= NC) {                           // ---- role B: d2 zero --
        const size_t base = (size_t)(blockIdx.x - NC) * 2048 + threadIdx.x * 8;
        *(float4*)&d2[base]     = make_float4(0.f, 0.f, 0.f, 0.f);
        *(float4*)&d2[base + 4] = make_float4(0.f, 0.f, 0.f, 0.f);
        return;
    }

    // ---- role A: 4-wave cooperative Gauss-Jordan (R16) ----
    const int c = blockIdx.x;
    const int tid = threadIdx.x;
    const int j = tid & 63;                           // column owned by lane
    const int w = tid >> 6;                           // wave -> rows 16w..16w+15
    const int rbase = w * 16;

    const float inv_nc = 1.0f / n[c];
    const float* __restrict__ Sc = S + (size_t)c * ND * ND + j;

    float4 B0, B1, B2, B3;
#define LOADR(u) {                                                   \
    const float x0 = Sc[(rbase + 4*(u) + 0) * ND] * inv_nc;          \
    const float x1 = Sc[(rbase + 4*(u) + 1) * ND] * inv_nc;          \
    const float x2 = Sc[(rbase + 4*(u) + 2) * ND] * inv_nc;          \
    const float x3 = Sc[(rbase + 4*(u) + 3) * ND] * inv_nc;          \
    B##u.x = (rbase + 4*(u) + 0 == j) ? x0 + 1e-6f : x0;             \
    B##u.y = (rbase + 4*(u) + 1 == j) ? x1 + 1e-6f : x1;             \
    B##u.z = (rbase + 4*(u) + 2 == j) ? x2 + 1e-6f : x2;             \
    B##u.w = (rbase + 4*(u) + 3 == j) ? x3 + 1e-6f : x3; }
    LOADR(0) LOADR(1) LOADR(2) LOADR(3)
#undef LOADR

#define UPD4(u, K) {                                                  \
    const float c0 = rlane(B##u.x, K);                                \
    const float c1 = rlane(B##u.y, K);                                \
    const float c2 = rlane(B##u.z, K);                                \
    const float c3 = rlane(B##u.w, K);                                \
    B##u.x = (om && (4*(u)+0 == ((K)&15))) ? rowk : B##u.x * am - c0 * rowk; \
    B##u.y = (om && (4*(u)+1 == ((K)&15))) ? rowk : B##u.y * am - c1 * rowk; \
    B##u.z = (om && (4*(u)+2 == ((K)&15))) ? rowk : B##u.z * am - c2 * rowk; \
    B##u.w = (om && (4*(u)+3 == ((K)&15))) ? rowk : B##u.w * am - c3 * rowk; \
}
#define STEPC(TL, C, K) {                                             \
    if (w == ((K) >> 4)) {                                            \
        const float rp = B##TL.C;         /* M[k][j]: own register */ \
        const float pv = rlane(rp, K);    /* pivot M[k][k] */         \
        const float ip = 1.0f / pv;                                   \
        rowbuf[(K) & 1][j] = (j == (K)) ? ip : rp * ip;               \
    }                                                                 \
    __syncthreads();                                                  \
    const float rowk = rowbuf[(K) & 1][j];                            \
    const float am = (j == (K)) ? 0.0f : 1.0f;                        \
    const bool om = (w == ((K) >> 4));                                \
    UPD4(0, K) UPD4(1, K) UPD4(2, K) UPD4(3, K)                       \
}
#define STEP4(T, TL) STEPC(TL, x, 4*(T)+0) STEPC(TL, y, 4*(T)+1) \
                     STEPC(TL, z, 4*(T)+2) STEPC(TL, w, 4*(T)+3)
#define FOR16P(M) M(0,0) M(1,1) M(2,2) M(3,3) M(4,0) M(5,1) M(6,2) M(7,3) \
                  M(8,0) M(9,1) M(10,2) M(11,3) M(12,0) M(13,1) M(14,2) M(15,3)
    FOR16P(STEP4)
#undef FOR16P
#undef STEP4
#undef STEPC
#undef UPD4

    // mirror Sinv into LDS for the pack gather (all 4 waves, disjoint rows)
#define MIR(u) *(float4*)&AcolS[j * (ND + 1) + rbase + 4*(u)] = B##u;
    MIR(0) MIR(1) MIR(2) MIR(3)
#undef MIR
    __syncthreads();                                  // AcolS complete

    if (w == 0) {                                     // y = Sinv*mu, kk, labels
        const float* __restrict__ muc = mu + (size_t)c * ND;
        float y = 0.f;
        #pragma unroll
        for (int t = 0; t < 16; ++t) {
            const float4 v = *(const float4*)&AcolS[j * (ND + 1) + 4 * t];
            y += v.x * muc[4*t]     + v.y * muc[4*t + 1]
               + v.z * muc[4*t + 2] + v.w * muc[4*t + 3];
        }
        cbuf[j] = -2.0f * y;                          // bvec values
        float kk = muc[j] * y;
        #pragma unroll
        for (int off = 32; off > 0; off >>= 1) kk += __shfl_down(kk, off);
        if (j == 0) {
            kksS[0] = kk;
            int lab = 0;
            for (int q = 0; q < NK; ++q) if (clab[c * NK + q] != 0) lab = q;
            labf[c] = (float)lab;
        }
    }
    __syncthreads();
    const float kks = kksS[0];

    unsigned short* __restrict__ ph = Bph + (size_t)c * KP;
    unsigned short* __restrict__ pl = Bpl + (size_t)c * KP;
    #pragma unroll
    for (int i = 0; i < 9; ++i) {                     // 34 iters split 4 ways
        const int t = w + 4 * i;
        if (t < KP / 64) {
            const int p = t * 64 + j;
            float val;
            if (p < NPAIR) {
                const uchar2 ed = edt[p];
                val = (ed.x == ed.y) ? AcolS[ed.x * (ND + 1) + ed.x]
                    : (AcolS[ed.y * (ND + 1) + ed.x] + AcolS[ed.x * (ND + 1) + ed.y]);
            } else if (p < KOFF) val = cbuf[p - BOFF];
            else if (p == KOFF)  val = kks;
            else                 val = 0.f;
            const unsigned short h = f2b(val);
            const unsigned short l = f2b(val - b2f(h));
            ph[p] = h;
            pl[p] = l;
        }
    }
}

// ---------------- d2 = Q·Beta^T, T3+T4 pipeline + T1 XCD remap --------------
// R19: arithmetic says gemm is L3-BANDWIDTH-bound: 512 blk x 17 kt x 40KB =
// 356MB staged; HBM only saw 71MB -> 285MB of B re-reads (x64) served by L3;
// 356MB / 54.5us = 6.5 TB/s = plausible L3 ceiling. Why L3 not L2: grid
// (64,2,4) round-robins consecutive lids (same (y,z) = same 1.1MB B-slice)
// across 8 XCDs -> every XCD touches all 8 B-slices (8.9MB > 4MB L2).
// Fix (T1 mechanism): decode tiles from lid so XCD j (= lid%8, m09) owns
// exactly one (y,z): nyz = lid&7 -> (y,z); nx = lid>>3 -> m-tile. 64 x-blocks
// per XCD = 32 CUs x 2 blocks, all sharing ONE L2-resident B-slice. Bijective
// (512 = 64*8). Same tiles, same arithmetic -> d2 bit-identical.
__global__ __launch_bounds__(256, 2) void gemm_kernel(
    const unsigned short* __restrict__ Qh, const unsigned short* __restrict__ Ql,
    const unsigned short* __restrict__ Bph, const unsigned short* __restrict__ Bpl,
    float* __restrict__ d2)
{
    __shared__ unsigned short AhS[2][64 * 32], AlS[2][64 * 32];   // 16KB
    __shared__ unsigned short BhS[2][256 * 32], BlS[2][256 * 32]; // 64KB

    const int tid  = threadIdx.x;
    const int lane = tid & 63, w = tid >> 6;
    const int quad = lane >> 4, rlo = lane & 15;

    // T1 XCD remap: lid%8 selects (y,z) -> one B-slice per XCD
    const int lid = blockIdx.x + 64 * blockIdx.y + 128 * blockIdx.z;
    const int nyz = lid & 7;
    const int m0 = (lid >> 3) * 64;               // sample tile
    const int n0 = (nyz & 1) * 256;               // cluster tile
    const int koff0 = (nyz >> 1) * KT_PER * 32;   // K-slice start

    // staging: thread -> LDS row tid>>2, slot tid&3 (dst linear = tid*16B);
    // source segment pre-swizzled so LDS[row][slot] = global seg slot^((row>>2)&3)
    const int srow = tid >> 2;
    const int sswz = (tid & 3) ^ ((srow >> 2) & 3);
    const unsigned short* aGh = Qh + (size_t)(m0 + srow) * KP + koff0 + sswz * 8;
    const unsigned short* aGl = Ql + (size_t)(m0 + srow) * KP + koff0 + sswz * 8;
    const unsigned short* bGh[4];
    const unsigned short* bGl[4];
    #pragma unroll
    for (int rd = 0; rd < 4; ++rd) {
        const size_t off = (size_t)(n0 + rd * 64 + srow) * KP + koff0 + sswz * 8;
        bGh[rd] = Bph + off;
        bGl[rd] = Bpl + off;
    }
    const int swz8 = (quad ^ ((rlo >> 2) & 3)) * 8;   // read-side slot

    floatx4 acc[4][4] = {};

#define STAGE(b, t) {                                                 \
        const int _ko = (t) * 32;                                     \
        gl16(aGh + _ko, &AhS[b][tid * 8]);                            \
        gl16(aGl + _ko, &AlS[b][tid * 8]);                            \
        _Pragma("unroll")                                             \
        for (int rd = 0; rd < 4; ++rd) {                              \
            gl16(bGh[rd] + _ko, &BhS[b][(rd * 256 + tid) * 8]);       \
            gl16(bGl[rd] + _ko, &BlS[b][(rd * 256 + tid) * 8]);       \
        } }

    // prologue: tiles 0 and 1 in flight; wait only for tile 0
    STAGE(0, 0)
    STAGE(1, 1)
    asm volatile("s_waitcnt vmcnt(10)" ::: "memory");
    __builtin_amdgcn_s_barrier();

    for (int kt = 0; kt < KT_PER; ++kt) {
        const int cur = kt & 1;

        short8 ah[4], al[4], bh[4], bl[4];
        #pragma unroll
        for (int i = 0; i < 4; ++i) {
            ah[i] = *(const short8*)&AhS[cur][(i * 16 + rlo) * 32 + swz8];
            al[i] = *(const short8*)&AlS[cur][(i * 16 + rlo) * 32 + swz8];
        }
        #pragma unroll
        for (int j2 = 0; j2 < 4; ++j2) {
            const int r = w * 64 + j2 * 16 + rlo;
            bh[j2] = *(const short8*)&BhS[cur][r * 32 + swz8];
            bl[j2] = *(const short8*)&BlS[cur][r * 32 + swz8];
        }
        asm volatile("s_waitcnt lgkmcnt(0)" ::: "memory");
        __builtin_amdgcn_sched_barrier(0);
        __builtin_amdgcn_s_barrier();     // all waves hold frags; cur reusable

        if (kt < KT_PER - 2) STAGE(cur, kt + 2)

        __builtin_amdgcn_s_setprio(1);
        #pragma unroll
        for (int i = 0; i < 4; ++i)
            #pragma unroll
            for (int j2 = 0; j2 < 4; ++j2) {
                acc[i][j2] = __builtin_amdgcn_mfma_f32_16x16x32_bf16(al[i], bh[j2], acc[i][j2], 0, 0, 0);
                acc[i][j2] = __builtin_amdgcn_mfma_f32_16x16x32_bf16(ah[i], bl[j2], acc[i][j2], 0, 0, 0);
                acc[i][j2] = __builtin_amdgcn_mfma_f32_16x16x32_bf16(ah[i], bh[j2], acc[i][j2], 0, 0, 0);
            }
        __builtin_amdgcn_s_setprio(0);

        if (kt < KT_PER - 2) {
            asm volatile("s_waitcnt vmcnt(10)" ::: "memory");  // kt+1 landed
        } else {
            asm volatile("s_waitcnt vmcnt(0)" ::: "memory");   // tail drain
        }
        __builtin_amdgcn_s_barrier();
    }
#undef STAGE

    // C layout (verified m89): col = lane&15, row = (lane>>4)*4 + reg
    #pragma unroll
    for (int i = 0; i < 4; ++i)
        #pragma unroll
        for (int j2 = 0; j2 < 4; ++j2) {
            const int m = m0 + i * 16 + quad * 4;
            const int nn = n0 + w * 64 + j2 * 16 + rlo;
            #pragma unroll
            for (int r = 0; r < 4; ++r)
                atomicAdd(&d2[(size_t)(m + r) * NC + nn], acc[i][j2][r]);
        }
}

// ---------------- scores / argmaxes: 4 waves/block, one sample per wave -----
__global__ __launch_bounds__(256) void score_kernel(
    const float* __restrict__ d2, const float* __restrict__ labf,
    float* __restrict__ out)
{
    const int s = blockIdx.x * 4 + (threadIdx.x >> 6);
    const int l = threadIdx.x & 63;

    float numer[NK];
    #pragma unroll
    for (int q = 0; q < NK; ++q) numer[q] = 0.f;
    float denom = 0.f, gmax = -1.f;
    int gidx = 0;

    #pragma unroll
    for (int i = 0; i < NC / 256; ++i) {         // float4 per lane, index-ascending
        const int c0 = i * 256 + l * 4;
        const float4 v = *(const float4*)&d2[(size_t)s * NC + c0];
        #pragma unroll
        for (int r = 0; r < 4; ++r) {
            const int c = c0 + r;
            const float G = __expf(-0.5f * ((const float*)&v)[r]);
            denom += G;
            const int lab = (int)labf[c];
            #pragma unroll
            for (int q = 0; q < NK; ++q) numer[q] += (q == lab) ? G : 0.f;
            if (G > gmax) { gmax = G; gidx = c; }   // strict > keeps first index
        }
    }

    #pragma unroll
    for (int off = 32; off > 0; off >>= 1) {
        const float og = __shfl_down(gmax, off);
        const int   oi = __shfl_down(gidx, off);
        if (og > gmax || (og == gmax && oi < gidx)) { gmax = og; gidx = oi; }
        denom += __shfl_down(denom, off);
        #pragma unroll
        for (int q = 0; q < NK; ++q) numer[q] += __shfl_down(numer[q], off);
    }

    if (l == 0) {
        const float inv = 1.0f / (denom + 1e-12f);
        float best = -1.f; int pk = 0;
        #pragma unroll
        for (int q = 0; q < NK; ++q) {
            const float sc = numer[q] * inv;
            out[(size_t)s * NK + q] = sc;
            if (sc > best) { best = sc; pk = q; }
        }
        out[(size_t)NS * NK + s]      = (float)pk;    // pred
        out[(size_t)NS * NK + NS + s] = (float)gidx;  // clusters
    }
}

extern "C" void kernel_launch(void* const* d_in, const int* in_sizes, int n_in,
                              void* d_out, int out_size, void* d_ws, size_t ws_size,
                              hipStream_t stream)
{
    const float* data = (const float*)d_in[0];
    const float* n    = (const float*)d_in[2];
    const float* mu   = (const float*)d_in[3];
    const float* S    = (const float*)d_in[4];
    const int*   clab = (const int*)d_in[5];

    char* w = (char*)d_ws;
    unsigned short* Qh  = (unsigned short*)(w);                 // 17,825,792 B
    unsigned short* Ql  = (unsigned short*)(w + 17825792);      // 17,825,792 B
    unsigned short* Bph = (unsigned short*)(w + 35651584);      //  2,228,224 B
    unsigned short* Bpl = (unsigned short*)(w + 37879808);      //  2,228,224 B
    float* d2   = (float*)(w + 40108032);                       //  8,388,608 B
    float* labf = (float*)(w + 48496640);                       //      2,048 B
    uchar2* edt = (uchar2*)(w + 48498688);                      //      4,352 B

    hipLaunchKernelGGL(table_kernel, dim3(1), dim3(64), 0, stream, edt);
    hipLaunchKernelGGL(prep_kernel,  dim3(NC + ZB + QB), dim3(256), 0, stream,
                       data, S, n, mu, clab, edt, Qh, Ql, Bph, Bpl, d2, labf);
    hipLaunchKernelGGL(gemm_kernel,  dim3(NS / 64, NC / 256, KSPLIT), dim3(256), 0, stream,
                       Qh, Ql, Bph, Bpl, d2);
    hipLaunchKernelGGL(score_kernel, dim3(NS / 4), dim3(256), 0, stream,
                       d2, labf, (float*)d_out);
}